// Round 9
// baseline (33.118 us; speedup 1.0000x reference)
//
#include <hip/hip_runtime.h>
#include <hip/hip_bf16.h>

// ---------------- compile-time problem constants ----------------
constexpr int LW    = 50;
constexpr int T     = 16384;
constexpr int NB    = 2;             // batch
constexpr int NK    = 11;            // ks = -5..5
constexpr int TOUT  = T - 2 * LW;    // 16284
constexpr int HALO  = 26;            // max |shift|
constexpr int ROWS  = 64;            // t-rows per block (4 waves x 16)
constexpr int NCOL  = 48;            // 46 used + 2 pad
constexpr int COLSTRIDE = 40;        // shorts per col within a chunk (80 B, 16B-aligned)
constexpr int CHUNK_SHORTS = 2048;   // 4096 B per staged B chunk (48*40=1920 used)

constexpr int count_mn() {
    int c = 0;
    for (int m = -25; m <= 25; ++m)
        for (int n = -25; n <= 25; ++n) {
            int p = m * n; if (p < 0) p = -p;
            if (p <= 25) ++c;
        }
    return c;
}
constexpr int NMN = count_mn();      // 449
static_assert(NMN == 449, "NMN");
constexpr int KTOT = 2 * NMN;        // 898 (even=Ar, odd=Ai)
constexpr int KSTEPS = (KTOT + 31) / 32;   // 29
constexpr int NSPLIT = 2;            // K-split factor
constexpr int SPLIT_STEPS = 15;      // ceil(29/2): split 0 -> 15 steps, split 1 -> 14
constexpr int OFFN = SPLIT_STEPS * 16;     // per-split off-table entries (240)

typedef __attribute__((ext_vector_type(8))) short short8;
typedef __attribute__((ext_vector_type(4))) float f32x4;

// precomputed Es element offsets per pair j: {-n, -(m+n), -m, 0}
struct OffTab { int4 v[NMN]; };
constexpr OffTab make_off() {
    OffTab t{};
    int idx = 0;
    for (int m = -25; m <= 25; ++m)
        for (int n = -25; n <= 25; ++n) {
            int p = m * n; if (p < 0) p = -p;
            if (p <= 25) {
                t.v[idx].x = -n;
                t.v[idx].y = -(m + n);
                t.v[idx].z = -m;
                t.v[idx].w = 0;
                ++idx;
            }
        }
    return t;
}
constexpr OffTab OFF_CONST = make_off();
__constant__ OffTab OFF = OFF_CONST;

// ---------------- per-batch runtime params ----------------
__device__ inline void batch_params(const float* __restrict__ ti, int b,
                                    int& ind, float& p3, float& p5) {
    float r = ti[b * 4 + 2] * (1.0f / 2.0e9f);
    int x = (int)r;
    ind = (x == 20) ? 0 : (x == 40) ? 1 : (x == 80) ? 2 : (x == 160) ? 3 : 0;
    float P = exp2f(ti[b * 4 + 0] * 0.1f * 3.3219280948873623f);   // 10^(ti0/10)
    float sp = sqrtf(P);
    p3 = P * sp;
    p5 = P * P * sp;
}

// ---------------- B-matrix pack kernel (R4-exact) ----------------
__global__ void pack_B(const float* __restrict__ ti,
                       const float* __restrict__ pCr, const float* __restrict__ pCi,
                       const float* __restrict__ C1r, const float* __restrict__ C1i,
                       const float* __restrict__ C2r, const float* __restrict__ C2i,
                       short* __restrict__ Bpack) {
    int idx = blockIdx.x * blockDim.x + threadIdx.x;
    constexpr int total = NB * KSTEPS * CHUNK_SHORTS;
    if (idx >= total) return;
    int b    = idx / (KSTEPS * CHUNK_SHORTS);
    int rem  = idx % (KSTEPS * CHUNK_SHORTS);
    int step = rem / CHUNK_SHORTS;
    int e    = rem % CHUNK_SHORTS;
    int col  = e / COLSTRIDE;
    int kk   = e % COLSTRIDE;
    float val = 0.f;
    if (col < 46 && kk < 32) {
        int K = step * 32 + kk;
        if (K < KTOT) {
            int m = K >> 1, comp = K & 1;
            int ind; float p3, p5;
            batch_params(ti, b, ind, p3, p5);
            if (col == 0)       val = comp ? -pCi[ind * NMN + m] : pCr[ind * NMN + m];
            else if (col == 1)  val = comp ?  pCr[ind * NMN + m] : pCi[ind * NMN + m];
            else {
                int q = (col - 2) >> 2, rr = (col - 2) & 3;
                size_t base = ((size_t)ind * NMN + m) * NK + q;
                if (rr == 0)      val = comp ? -C1i[base] : C1r[base];
                else if (rr == 1) val = comp ?  C1r[base] : C1i[base];
                else if (rr == 2) val = comp ?  C2i[base] : C2r[base];
                else              val = comp ? -C2r[base] : C2i[base];
            }
        }
    }
    Bpack[idx] = __builtin_bit_cast(short, __float2bfloat16(val));
}

// ---------------- main MFMA kernel, K-split ----------------
// grid (ceil(TOUT/64), NB, NSPLIT), block 256 = 4 waves x 16 rows.
// Inner loop structure is R8-verbatim; only the K-step range is parameterized.
// Writes 64x48 f32 partial accumulators to `part` (no epilogue here).
__global__ __launch_bounds__(256) void sopbc_mfma_split(
    const float* __restrict__ Er, const float* __restrict__ Ei,
    const short* __restrict__ Bpack,
    float* __restrict__ part)
{
    const int b   = blockIdx.y;
    const int bx  = blockIdx.x;
    const int s   = blockIdx.z;
    const int ks0 = s * SPLIT_STEPS;
    const int nks = (KSTEPS - ks0 < SPLIT_STEPS) ? (KSTEPS - ks0) : SPLIT_STEPS;
    const int tid = threadIdx.x;
    const int lane = tid & 63;
    const int w    = tid >> 6;        // wave 0..3
    const int lr   = lane & 15;       // 16-dim index (A-row / B-col / D-col)
    const int g    = lane >> 4;       // k-group 0..3
    const int t0   = LW + bx * ROWS;

    __shared__ float2 Es[ROWS + 2 * HALO + 1];       // 117
    __shared__ int4   off_lds[OFFN];                 // 240 * 16B
    __shared__ short  Bbuf[3][CHUNK_SHORTS];         // 3 x 4 KB
    __shared__ float  res[ROWS][NCOL + 1];           // 64 x 49 f32

    // ---- prologue staging ----
    for (int i = tid; i < ROWS + 2 * HALO + 1; i += 256) {
        int tt = t0 - HALO + i;                      // >= 24 always
        float2 v = {0.f, 0.f};
        if (tt < T) { v.x = Er[(size_t)b * T + tt]; v.y = Ei[(size_t)b * T + tt]; }
        Es[i] = v;
    }
    for (int i = tid; i < OFFN; i += 256) {
        int gm = ks0 * 16 + i;                       // global m index
        int4 v = {0, 0, 0, 0};
        if (gm < NMN) v = OFF.v[gm];
        off_lds[i] = v;
    }

    const short* gbase = Bpack + (size_t)b * KSTEPS * CHUNK_SHORTS;
    auto stage = [&](int bufIdx, int chunk) {        // chunk is ABSOLUTE step index
        const short* gsrc = gbase + (size_t)chunk * CHUNK_SHORTS + w * 512 + lane * 8;
        const short* ldst = &Bbuf[bufIdx][w * 512];  // wave-uniform base; lanes auto-offset x16B
        __builtin_amdgcn_global_load_lds(
            (const __attribute__((address_space(1))) void*)gsrc,
            (__attribute__((address_space(3))) void*)ldst,
            16, 0, 0);
    };

    stage(0, ks0);
    stage(1, ks0 + 1);
    __syncthreads();                                  // full drain once at prologue

    const int esb = w * 16 + lr + HALO;               // Es element base for this lane's row

    f32x4 acc0 = {0.f, 0.f, 0.f, 0.f};
    f32x4 acc1 = {0.f, 0.f, 0.f, 0.f};
    f32x4 acc2 = {0.f, 0.f, 0.f, 0.f};

    int cur = 0;
    for (int i = 0; i < nks; ++i) {
        // chunk ks0+i landed (counted vmcnt: 2 outstanding at this point)
        asm volatile("s_waitcnt vmcnt(1)" ::: "memory");
        __builtin_amdgcn_s_barrier();

        // prefetch chunk ks0+i+2 (clamped dup at the tail keeps vmcnt count uniform)
        int pc = (i + 2 < nks) ? (ks0 + i + 2) : (ks0 + nks - 1);
        int pbuf = cur + 2; if (pbuf >= 3) pbuf -= 3;
        stage(pbuf, pc);

        // B fragments: lane holds B[k=g*8+j][col=lr+16*cf], 8 consecutive k
        const short* bb = &Bbuf[cur][0];
        short8 b0 = *(const short8*)(bb + (0 * 16 + lr) * COLSTRIDE + g * 8);
        short8 b1 = *(const short8*)(bb + (1 * 16 + lr) * COLSTRIDE + g * 8);
        short8 b2 = *(const short8*)(bb + (2 * 16 + lr) * COLSTRIDE + g * 8);

        // A fragment: lane holds A[row=lr][k=g*8+j]; k=2p+comp -> local m = i*16+g*4+p
        short8 af;
        const int m0 = i * 16 + g * 4;
#pragma unroll
        for (int p = 0; p < 4; ++p) {
            const int4 o = off_lds[m0 + p];
            const float2 en  = Es[esb + o.x];
            const float2 emn = Es[esb + o.y];
            const float2 em  = Es[esb + o.z];
            const float ar1 = en.x * emn.x + en.y * emn.y;
            const float ai1 = en.y * emn.x - en.x * emn.y;
            const float Ar = ar1 * em.x - ai1 * em.y;
            const float Ai = ar1 * em.y + ai1 * em.x;
            af[2 * p]     = __builtin_bit_cast(short, __float2bfloat16(Ar));
            af[2 * p + 1] = __builtin_bit_cast(short, __float2bfloat16(Ai));
        }

        acc0 = __builtin_amdgcn_mfma_f32_16x16x32_bf16(af, b0, acc0, 0, 0, 0);
        acc1 = __builtin_amdgcn_mfma_f32_16x16x32_bf16(af, b1, acc1, 0, 0, 0);
        acc2 = __builtin_amdgcn_mfma_f32_16x16x32_bf16(af, b2, acc2, 0, 0, 0);

        cur = (cur + 1 == 3) ? 0 : cur + 1;
    }

    // ---- write accumulators to LDS: D[row=g*4+reg][col=lr+16*cf] ----
    const int orow = w * 16 + g * 4;
#pragma unroll
    for (int r = 0; r < 4; ++r) {
        res[orow + r][lr]      = acc0[r];
        res[orow + r][lr + 16] = acc1[r];
        res[orow + r][lr + 32] = acc2[r];
    }
    __syncthreads();

    // ---- copy partial tile to global ws (coalesced 4B stores) ----
    float* pdst = part + (((size_t)bx * NB + b) * NSPLIT + s) * (ROWS * NCOL);
    for (int idx2 = tid; idx2 < ROWS * NCOL; idx2 += 256)
        pdst[idx2] = res[idx2 / NCOL][idx2 % NCOL];
}

// ---------------- combine + epilogue kernel ----------------
// one thread per (b, t') output sample
__global__ __launch_bounds__(256) void sopbc_combine(
    const float* __restrict__ Er, const float* __restrict__ Ei,
    const float* __restrict__ ti,
    const float* __restrict__ part,
    float* __restrict__ out)
{
    const int gid = blockIdx.x * 256 + threadIdx.x;
    if (gid >= NB * TOUT) return;
    const int b  = gid / TOUT;
    const int tp = gid % TOUT;
    const int bx = tp >> 6;          // t-block
    const int r  = tp & 63;          // row within block
    const int t  = tp + LW;

    int ind; float p3, p5;
    batch_params(ti, b, ind, p3, p5);

    const float* p0 = part + (((size_t)bx * NB + b) * NSPLIT + 0) * (ROWS * NCOL) + r * NCOL;
    const float* p1 = part + (((size_t)bx * NB + b) * NSPLIT + 1) * (ROWS * NCOL) + r * NCOL;

    float v[46];
#pragma unroll
    for (int c = 0; c < 46; ++c) v[c] = p0[c] + p1[c];

    const float s1r = v[0], s1i = v[1];
    float accr = 0.f, acci = 0.f;
#pragma unroll
    for (int k = 0; k < NK; ++k) {
        const float ex = Er[(size_t)b * T + t + 5 - k];   // E[t-(k-5)]
        const float ey = Ei[(size_t)b * T + t + 5 - k];
        const float Iv = ex * ex + ey * ey;
        const float Qr = ex * ex - ey * ey;
        const float Qi = 2.f * ex * ey;
        const float g1r = v[2 + 4 * k], g1i = v[3 + 4 * k];
        const float g2r = v[4 + 4 * k], g2i = v[5 + 4 * k];
        accr += Iv * g1r + Qr * g2r - Qi * g2i;
        acci += Iv * g1i + Qr * g2i + Qi * g2r;
    }
    const float ecx = Er[(size_t)b * T + t];
    const float ecy = Ei[(size_t)b * T + t];
    const float outr = ecx + p3 * s1r + p5 * accr;
    const float outi = ecy + p3 * s1i + p5 * acci;
    const size_t o = ((size_t)b * TOUT + tp) * 2;
    out[o]     = outr;
    out[o + 1] = outi;
}

// ---------------- scalar fallback (single pass, fp32 exact) ----------------
__global__ __launch_bounds__(256) void sopbc_scalar(
    const float* __restrict__ Er, const float* __restrict__ Ei,
    const float* __restrict__ ti,
    const float* __restrict__ pCr, const float* __restrict__ pCi,
    const float* __restrict__ C1r, const float* __restrict__ C1i,
    const float* __restrict__ C2r, const float* __restrict__ C2i,
    float* __restrict__ out)
{
    const int b = blockIdx.y;
    const int t0 = LW + blockIdx.x * 256;
    const int tid = threadIdx.x;

    int ind; float p3, p5;
    batch_params(ti, b, ind, p3, p5);

    __shared__ float2 Ess[256 + 2 * HALO + 1];
    for (int i = tid; i < 256 + 2 * HALO + 1; i += 256) {
        int tt = t0 - HALO + i;
        float2 v = {0.f, 0.f};
        if (tt >= 0 && tt < T) { v.x = Er[(size_t)b * T + tt]; v.y = Ei[(size_t)b * T + tt]; }
        Ess[i] = v;
    }
    __syncthreads();

    const int t = t0 + tid;
    const int base = tid + HALO;

    float Iv[NK], Qr[NK], Qi[NK];
#pragma unroll
    for (int k = 0; k < NK; ++k) {
        const float2 ek = Ess[base + 5 - k];
        Iv[k] = ek.x * ek.x + ek.y * ek.y;
        Qr[k] = ek.x * ek.x - ek.y * ek.y;
        Qi[k] = 2.f * ek.x * ek.y;
    }

    float s1r = 0.f, s1i = 0.f, accr = 0.f, acci = 0.f;
    const float* cpr = pCr + (size_t)ind * NMN;
    const float* cpi = pCi + (size_t)ind * NMN;
    const float* a1r = C1r + (size_t)ind * NMN * NK;
    const float* a1i = C1i + (size_t)ind * NMN * NK;
    const float* a2r = C2r + (size_t)ind * NMN * NK;
    const float* a2i = C2i + (size_t)ind * NMN * NK;

    for (int j = 0; j < NMN; ++j) {
        const int4 off = OFF.v[j];
        const float2 en  = Ess[base + off.x];
        const float2 emn = Ess[base + off.y];
        const float2 em  = Ess[base + off.z];
        const float ar1 = en.x * emn.x + en.y * emn.y;
        const float ai1 = en.y * emn.x - en.x * emn.y;
        const float Ar = ar1 * em.x - ai1 * em.y;
        const float Ai = ar1 * em.y + ai1 * em.x;

        float P1 = 0.f, P2 = 0.f, P3 = 0.f, P4 = 0.f, P5 = 0.f, P6 = 0.f;
#pragma unroll
        for (int k = 0; k < NK; ++k) {
            const float x1 = a1r[j * NK + k], y1 = a1i[j * NK + k];
            const float x2 = a2r[j * NK + k], y2 = a2i[j * NK + k];
            P1 += Iv[k] * x1;  P2 += Iv[k] * y1;
            P3 += Qr[k] * x2;  P4 += Qr[k] * y2;
            P5 += Qi[k] * x2;  P6 += Qi[k] * y2;
        }
        const float c0 = cpr[j], c1 = cpi[j];
        s1r += Ar * c0 - Ai * c1;
        s1i += Ar * c1 + Ai * c0;
        const float U = P1, V = P2, W = P3 - P6, Z = P4 + P5;
        accr += Ar * (U + W) + Ai * (Z - V);
        acci += Ar * (V + Z) + Ai * (U - W);
    }

    if (t < T - LW) {
        const float2 e = Ess[base];
        const size_t o = ((size_t)b * TOUT + (size_t)(t - LW)) * 2;
        out[o]     = e.x + p3 * s1r + p5 * accr;
        out[o + 1] = e.y + p3 * s1i + p5 * acci;
    }
}

// ---------------- launch ----------------
extern "C" void kernel_launch(void* const* d_in, const int* in_sizes, int n_in,
                              void* d_out, int out_size, void* d_ws, size_t ws_size,
                              hipStream_t stream) {
    const float* Er  = (const float*)d_in[0];
    const float* Ei  = (const float*)d_in[1];
    const float* ti  = (const float*)d_in[2];
    const float* pCr = (const float*)d_in[3];
    const float* pCi = (const float*)d_in[4];
    const float* C1r = (const float*)d_in[5];
    const float* C1i = (const float*)d_in[6];
    const float* C2r = (const float*)d_in[7];
    const float* C2i = (const float*)d_in[8];
    float* out = (float*)d_out;

    const int nblk = (TOUT + ROWS - 1) / ROWS;        // 255
    const size_t packBytes = (size_t)NB * KSTEPS * CHUNK_SHORTS * sizeof(short);
    const size_t partOff   = (packBytes + 255) & ~(size_t)255;
    const size_t partBytes = (size_t)nblk * NB * NSPLIT * ROWS * NCOL * sizeof(float);

    if (ws_size >= partOff + partBytes) {
        short* Bpack = (short*)d_ws;
        float* part  = (float*)((char*)d_ws + partOff);
        constexpr int total = NB * KSTEPS * CHUNK_SHORTS;
        hipLaunchKernelGGL(pack_B, dim3((total + 255) / 256), dim3(256), 0, stream,
                           ti, pCr, pCi, C1r, C1i, C2r, C2i, Bpack);
        hipLaunchKernelGGL(sopbc_mfma_split, dim3(nblk, NB, NSPLIT), dim3(256), 0, stream,
                           Er, Ei, Bpack, part);
        const int ncomb = (NB * TOUT + 255) / 256;
        hipLaunchKernelGGL(sopbc_combine, dim3(ncomb), dim3(256), 0, stream,
                           Er, Ei, ti, part, out);
    } else {
        const int nblk2 = (TOUT + 255) / 256;
        hipLaunchKernelGGL(sopbc_scalar, dim3(nblk2, NB), dim3(256), 0, stream,
                           Er, Ei, ti, pCr, pCi, C1r, C1i, C2r, C2i, out);
    }
}

// Round 11
// 19.682 us; speedup vs baseline: 1.6826x; 1.6826x over previous
//
#include <hip/hip_runtime.h>
#include <hip/hip_bf16.h>

// ---------------- compile-time problem constants ----------------
constexpr int LW    = 50;
constexpr int T     = 16384;
constexpr int NB    = 2;             // batch
constexpr int NK    = 11;            // ks = -5..5
constexpr int TOUT  = T - 2 * LW;    // 16284
constexpr int HALO  = 26;            // max |shift|
constexpr int ROWS  = 64;            // t-rows per block (4 waves x 16)
constexpr int NCOL  = 48;            // 46 used + 2 pad
constexpr int COLSTRIDE = 40;        // shorts per col within a chunk (80 B, 16B-aligned)
constexpr int CHUNK_SHORTS = 2048;   // 4096 B per staged B chunk (48*40=1920 used)

constexpr int count_mn() {
    int c = 0;
    for (int m = -25; m <= 25; ++m)
        for (int n = -25; n <= 25; ++n) {
            int p = m * n; if (p < 0) p = -p;
            if (p <= 25) ++c;
        }
    return c;
}
constexpr int NMN = count_mn();      // 449 (original list)
static_assert(NMN == 449, "NMN");

// merged canonical pairs (m<=n): A(m,n)==A(n,m), coefficients add linearly
constexpr int count_merged() {
    int c = 0;
    for (int m = -25; m <= 25; ++m)
        for (int n = -25; n <= 25; ++n) {
            int p = m * n; if (p < 0) p = -p;
            if (p <= 25 && m <= n) ++c;
        }
    return c;
}
constexpr int NMN2 = count_merged(); // 230
static_assert(NMN2 == 230, "NMN2");
constexpr int KTOT2   = 2 * NMN2;          // 460 (even=Ar, odd=Ai)
constexpr int KSTEPS2 = (KTOT2 + 31) / 32; // 15
constexpr int MPAD2   = KSTEPS2 * 16;      // 240 padded merged entries

typedef __attribute__((ext_vector_type(8))) short short8;
typedef __attribute__((ext_vector_type(4))) float f32x4;

// merged tables: Es offsets (canonical (m,n)) + original flat indices of the
// two coefficient sources (idx1 == idx2 on the diagonal). Pad -> off {0,0,0,0},
// idx 0 (B columns are zero for K >= KTOT2, so pad A value multiplies zero).
struct MergedTab { int4 off[MPAD2]; int idx1[MPAD2]; int idx2[MPAD2]; };
constexpr MergedTab make_merged() {
    MergedTab t{};
    signed char om[NMN] = {}, on[NMN] = {};
    int j = 0;
    for (int m = -25; m <= 25; ++m)
        for (int n = -25; n <= 25; ++n) {
            int p = m * n; if (p < 0) p = -p;
            if (p <= 25) { om[j] = (signed char)m; on[j] = (signed char)n; ++j; }
        }
    int k = 0;
    for (int j1 = 0; j1 < NMN; ++j1) {
        int m = om[j1], n = on[j1];
        if (m > n) continue;
        int j2 = j1;
        if (m != n) {
            for (int q = 0; q < NMN; ++q)
                if (om[q] == n && on[q] == m) { j2 = q; break; }
        }
        t.off[k].x = -n;
        t.off[k].y = -(m + n);
        t.off[k].z = -m;
        t.off[k].w = 0;
        t.idx1[k] = j1;
        t.idx2[k] = j2;
        ++k;
    }
    for (; k < MPAD2; ++k) {
        t.off[k].x = 0; t.off[k].y = 0; t.off[k].z = 0; t.off[k].w = 0;
        t.idx1[k] = 0;  t.idx2[k] = 0;
    }
    return t;
}
constexpr MergedTab MERGED_CONST = make_merged();
__constant__ MergedTab MERGED = MERGED_CONST;

// original offset table for the scalar fallback
struct OffTab { int4 v[NMN]; };
constexpr OffTab make_off() {
    OffTab t{};
    int idx = 0;
    for (int m = -25; m <= 25; ++m)
        for (int n = -25; n <= 25; ++n) {
            int p = m * n; if (p < 0) p = -p;
            if (p <= 25) {
                t.v[idx].x = -n; t.v[idx].y = -(m + n); t.v[idx].z = -m; t.v[idx].w = 0;
                ++idx;
            }
        }
    return t;
}
constexpr OffTab OFF_CONST = make_off();
__constant__ OffTab OFF = OFF_CONST;

// ---------------- per-batch runtime params ----------------
__device__ inline void batch_params(const float* __restrict__ ti, int b,
                                    int& ind, float& p3, float& p5) {
    float r = ti[b * 4 + 2] * (1.0f / 2.0e9f);
    int x = (int)r;
    ind = (x == 20) ? 0 : (x == 40) ? 1 : (x == 80) ? 2 : (x == 160) ? 3 : 0;
    float P = exp2f(ti[b * 4 + 0] * 0.1f * 3.3219280948873623f);   // 10^(ti0/10)
    float sp = sqrtf(P);
    p3 = P * sp;
    p5 = P * P * sp;
}

// per-original-index coefficient with component/column swizzle (R8-exact logic)
__device__ inline float coeff_val(int j, int comp, int col, int ind,
                                  const float* __restrict__ pCr, const float* __restrict__ pCi,
                                  const float* __restrict__ C1r, const float* __restrict__ C1i,
                                  const float* __restrict__ C2r, const float* __restrict__ C2i) {
    if (col == 0) return comp ? -pCi[ind * NMN + j] : pCr[ind * NMN + j];
    if (col == 1) return comp ?  pCr[ind * NMN + j] : pCi[ind * NMN + j];
    int q = (col - 2) >> 2, rr = (col - 2) & 3;
    size_t base = ((size_t)ind * NMN + j) * NK + q;
    if (rr == 0) return comp ? -C1i[base] : C1r[base];
    if (rr == 1) return comp ?  C1r[base] : C1i[base];
    if (rr == 2) return comp ?  C2i[base] : C2r[base];
    return comp ? -C2r[base] : C2i[base];
}

// ---------------- B-matrix pack kernel (merged pairs) ----------------
// Bpack[b][step][col][kk] bf16, col stride COLSTRIDE, chunk stride CHUNK_SHORTS.
// K = step*32+kk ; merged m' = K>>1 ; comp = K&1. val = C[j1] (+ C[j2] if j2!=j1).
__global__ void pack_B(const float* __restrict__ ti,
                       const float* __restrict__ pCr, const float* __restrict__ pCi,
                       const float* __restrict__ C1r, const float* __restrict__ C1i,
                       const float* __restrict__ C2r, const float* __restrict__ C2i,
                       short* __restrict__ Bpack) {
    int idx = blockIdx.x * blockDim.x + threadIdx.x;
    constexpr int total = NB * KSTEPS2 * CHUNK_SHORTS;
    if (idx >= total) return;
    int b    = idx / (KSTEPS2 * CHUNK_SHORTS);
    int rem  = idx % (KSTEPS2 * CHUNK_SHORTS);
    int step = rem / CHUNK_SHORTS;
    int e    = rem % CHUNK_SHORTS;
    int col  = e / COLSTRIDE;
    int kk   = e % COLSTRIDE;
    float val = 0.f;
    if (col < 46 && kk < 32) {
        int K = step * 32 + kk;
        if (K < KTOT2) {
            int mp = K >> 1, comp = K & 1;
            int ind; float p3, p5;
            batch_params(ti, b, ind, p3, p5);
            int j1 = MERGED.idx1[mp], j2 = MERGED.idx2[mp];
            val = coeff_val(j1, comp, col, ind, pCr, pCi, C1r, C1i, C2r, C2i);
            if (j2 != j1)
                val += coeff_val(j2, comp, col, ind, pCr, pCi, C1r, C1i, C2r, C2i);
        }
    }
    Bpack[idx] = __builtin_bit_cast(short, __float2bfloat16(val));
}

// ---------------- main MFMA kernel (R8-frozen loop structure) ----------------
// grid (ceil(TOUT/64), NB), block 256 = 4 waves x 16 rows.
__global__ __launch_bounds__(256) void sopbc_mfma(
    const float* __restrict__ Er, const float* __restrict__ Ei,
    const float* __restrict__ ti,
    const short* __restrict__ Bpack,
    float* __restrict__ out)
{
    const int b   = blockIdx.y;
    const int bx  = blockIdx.x;
    const int tid = threadIdx.x;
    const int lane = tid & 63;
    const int w    = tid >> 6;        // wave 0..3
    const int lr   = lane & 15;       // 16-dim index (A-row / B-col / D-col)
    const int g    = lane >> 4;       // k-group 0..3
    const int t0   = LW + bx * ROWS;

    int ind; float p3, p5;
    batch_params(ti, b, ind, p3, p5);

    __shared__ float2 Es[ROWS + 2 * HALO + 1];       // 117
    __shared__ int4   off_lds[MPAD2];                // 240 * 16B
    __shared__ short  Bbuf[3][CHUNK_SHORTS];         // 3 x 4 KB
    __shared__ float  res[ROWS][NCOL + 1];           // 64 x 49 f32

    // ---- prologue staging ----
    for (int i = tid; i < ROWS + 2 * HALO + 1; i += 256) {
        int tt = t0 - HALO + i;                      // >= 24 always
        float2 v = {0.f, 0.f};
        if (tt < T) { v.x = Er[(size_t)b * T + tt]; v.y = Ei[(size_t)b * T + tt]; }
        Es[i] = v;
    }
    for (int i = tid; i < MPAD2; i += 256)
        off_lds[i] = MERGED.off[i];                  // table pre-padded

    const short* gbase = Bpack + (size_t)b * KSTEPS2 * CHUNK_SHORTS;
    auto stage = [&](int bufIdx, int chunk) {
        const short* gsrc = gbase + (size_t)chunk * CHUNK_SHORTS + w * 512 + lane * 8;
        const short* ldst = &Bbuf[bufIdx][w * 512];   // wave-uniform base; lanes auto-offset x16B
        __builtin_amdgcn_global_load_lds(
            (const __attribute__((address_space(1))) void*)gsrc,
            (__attribute__((address_space(3))) void*)ldst,
            16, 0, 0);
    };

    stage(0, 0);
    stage(1, 1);
    __syncthreads();                                  // full drain once at prologue

    const int esb = w * 16 + lr + HALO;               // Es element base for this lane's row

    f32x4 acc0 = {0.f, 0.f, 0.f, 0.f};
    f32x4 acc1 = {0.f, 0.f, 0.f, 0.f};
    f32x4 acc2 = {0.f, 0.f, 0.f, 0.f};

    int cur = 0;
    for (int i = 0; i < KSTEPS2; ++i) {
        // chunk i landed (counted vmcnt: outstanding = {i, i+1} at this point)
        asm volatile("s_waitcnt vmcnt(1)" ::: "memory");
        __builtin_amdgcn_s_barrier();

        // prefetch chunk i+2 (clamped dup at the tail keeps the vmcnt count uniform)
        int pc = (i + 2 < KSTEPS2) ? (i + 2) : (KSTEPS2 - 1);
        int pbuf = cur + 2; if (pbuf >= 3) pbuf -= 3;
        stage(pbuf, pc);

        // B fragments: lane holds B[k=g*8+j][col=lr+16*cf], 8 consecutive k
        const short* bb = &Bbuf[cur][0];
        short8 b0 = *(const short8*)(bb + (0 * 16 + lr) * COLSTRIDE + g * 8);
        short8 b1 = *(const short8*)(bb + (1 * 16 + lr) * COLSTRIDE + g * 8);
        short8 b2 = *(const short8*)(bb + (2 * 16 + lr) * COLSTRIDE + g * 8);

        // A fragment: lane holds A[row=lr][k=g*8+j]; k=2p+comp -> m' = i*16+g*4+p
        short8 af;
        const int m0 = i * 16 + g * 4;
#pragma unroll
        for (int p = 0; p < 4; ++p) {
            const int4 o = off_lds[m0 + p];
            const float2 en  = Es[esb + o.x];
            const float2 emn = Es[esb + o.y];
            const float2 em  = Es[esb + o.z];
            const float ar1 = en.x * emn.x + en.y * emn.y;
            const float ai1 = en.y * emn.x - en.x * emn.y;
            const float Ar = ar1 * em.x - ai1 * em.y;
            const float Ai = ar1 * em.y + ai1 * em.x;
            af[2 * p]     = __builtin_bit_cast(short, __float2bfloat16(Ar));
            af[2 * p + 1] = __builtin_bit_cast(short, __float2bfloat16(Ai));
        }

        acc0 = __builtin_amdgcn_mfma_f32_16x16x32_bf16(af, b0, acc0, 0, 0, 0);
        acc1 = __builtin_amdgcn_mfma_f32_16x16x32_bf16(af, b1, acc1, 0, 0, 0);
        acc2 = __builtin_amdgcn_mfma_f32_16x16x32_bf16(af, b2, acc2, 0, 0, 0);

        cur = (cur + 1 == 3) ? 0 : cur + 1;
    }

    // ---- write accumulators to LDS: D[row=g*4+reg][col=lr+16*cf] ----
    const int orow = w * 16 + g * 4;
#pragma unroll
    for (int r = 0; r < 4; ++r) {
        res[orow + r][lr]      = acc0[r];
        res[orow + r][lr + 16] = acc1[r];
        res[orow + r][lr + 32] = acc2[r];
    }
    __syncthreads();

    // ---- epilogue: one thread per row ----
    if (tid < ROWS) {
        const int r = tid;
        const int t = t0 + r;
        if (t < T - LW) {
            const float s1r = res[r][0], s1i = res[r][1];
            float accr = 0.f, acci = 0.f;
#pragma unroll
            for (int k = 0; k < NK; ++k) {
                const float2 ek = Es[r + HALO + 5 - k];     // E[t-(k-5)]
                const float Iv = ek.x * ek.x + ek.y * ek.y;
                const float Qr = ek.x * ek.x - ek.y * ek.y;
                const float Qi = 2.f * ek.x * ek.y;
                const float g1r = res[r][2 + 4 * k], g1i = res[r][3 + 4 * k];
                const float g2r = res[r][4 + 4 * k], g2i = res[r][5 + 4 * k];
                accr += Iv * g1r + Qr * g2r - Qi * g2i;
                acci += Iv * g1i + Qr * g2i + Qi * g2r;
            }
            const float2 e = Es[r + HALO];
            const float outr = e.x + p3 * s1r + p5 * accr;
            const float outi = e.y + p3 * s1i + p5 * acci;
            const size_t o = ((size_t)b * TOUT + (size_t)(t - LW)) * 2;
            out[o]     = outr;
            out[o + 1] = outi;
        }
    }
}

// ---------------- scalar fallback (single pass, fp32 exact) ----------------
__global__ __launch_bounds__(256) void sopbc_scalar(
    const float* __restrict__ Er, const float* __restrict__ Ei,
    const float* __restrict__ ti,
    const float* __restrict__ pCr, const float* __restrict__ pCi,
    const float* __restrict__ C1r, const float* __restrict__ C1i,
    const float* __restrict__ C2r, const float* __restrict__ C2i,
    float* __restrict__ out)
{
    const int b = blockIdx.y;
    const int t0 = LW + blockIdx.x * 256;
    const int tid = threadIdx.x;

    int ind; float p3, p5;
    batch_params(ti, b, ind, p3, p5);

    __shared__ float2 Ess[256 + 2 * HALO + 1];
    for (int i = tid; i < 256 + 2 * HALO + 1; i += 256) {
        int tt = t0 - HALO + i;
        float2 v = {0.f, 0.f};
        if (tt >= 0 && tt < T) { v.x = Er[(size_t)b * T + tt]; v.y = Ei[(size_t)b * T + tt]; }
        Ess[i] = v;
    }
    __syncthreads();

    const int t = t0 + tid;
    const int base = tid + HALO;

    float Iv[NK], Qr[NK], Qi[NK];
#pragma unroll
    for (int k = 0; k < NK; ++k) {
        const float2 ek = Ess[base + 5 - k];
        Iv[k] = ek.x * ek.x + ek.y * ek.y;
        Qr[k] = ek.x * ek.x - ek.y * ek.y;
        Qi[k] = 2.f * ek.x * ek.y;
    }

    float s1r = 0.f, s1i = 0.f, accr = 0.f, acci = 0.f;
    const float* cpr = pCr + (size_t)ind * NMN;
    const float* cpi = pCi + (size_t)ind * NMN;
    const float* a1r = C1r + (size_t)ind * NMN * NK;
    const float* a1i = C1i + (size_t)ind * NMN * NK;
    const float* a2r = C2r + (size_t)ind * NMN * NK;
    const float* a2i = C2i + (size_t)ind * NMN * NK;

    for (int j = 0; j < NMN; ++j) {
        const int4 off = OFF.v[j];
        const float2 en  = Ess[base + off.x];
        const float2 emn = Ess[base + off.y];
        const float2 em  = Ess[base + off.z];
        const float ar1 = en.x * emn.x + en.y * emn.y;
        const float ai1 = en.y * emn.x - en.x * emn.y;
        const float Ar = ar1 * em.x - ai1 * em.y;
        const float Ai = ar1 * em.y + ai1 * em.x;

        float P1 = 0.f, P2 = 0.f, P3 = 0.f, P4 = 0.f, P5 = 0.f, P6 = 0.f;
#pragma unroll
        for (int k = 0; k < NK; ++k) {
            const float x1 = a1r[j * NK + k], y1 = a1i[j * NK + k];
            const float x2 = a2r[j * NK + k], y2 = a2i[j * NK + k];
            P1 += Iv[k] * x1;  P2 += Iv[k] * y1;
            P3 += Qr[k] * x2;  P4 += Qr[k] * y2;
            P5 += Qi[k] * x2;  P6 += Qi[k] * y2;
        }
        const float c0 = cpr[j], c1 = cpi[j];
        s1r += Ar * c0 - Ai * c1;
        s1i += Ar * c1 + Ai * c0;
        const float U = P1, V = P2, W = P3 - P6, Z = P4 + P5;
        accr += Ar * (U + W) + Ai * (Z - V);
        acci += Ar * (V + Z) + Ai * (U - W);
    }

    if (t < T - LW) {
        const float2 e = Ess[base];
        const size_t o = ((size_t)b * TOUT + (size_t)(t - LW)) * 2;
        out[o]     = e.x + p3 * s1r + p5 * accr;
        out[o + 1] = e.y + p3 * s1i + p5 * acci;
    }
}

// ---------------- launch ----------------
extern "C" void kernel_launch(void* const* d_in, const int* in_sizes, int n_in,
                              void* d_out, int out_size, void* d_ws, size_t ws_size,
                              hipStream_t stream) {
    const float* Er  = (const float*)d_in[0];
    const float* Ei  = (const float*)d_in[1];
    const float* ti  = (const float*)d_in[2];
    const float* pCr = (const float*)d_in[3];
    const float* pCi = (const float*)d_in[4];
    const float* C1r = (const float*)d_in[5];
    const float* C1i = (const float*)d_in[6];
    const float* C2r = (const float*)d_in[7];
    const float* C2i = (const float*)d_in[8];
    float* out = (float*)d_out;

    const size_t packBytes = (size_t)NB * KSTEPS2 * CHUNK_SHORTS * sizeof(short);

    if (ws_size >= packBytes) {
        short* Bpack = (short*)d_ws;
        constexpr int total = NB * KSTEPS2 * CHUNK_SHORTS;
        hipLaunchKernelGGL(pack_B, dim3((total + 255) / 256), dim3(256), 0, stream,
                           ti, pCr, pCi, C1r, C1i, C2r, C2i, Bpack);
        const int nblk = (TOUT + ROWS - 1) / ROWS;    // 255
        hipLaunchKernelGGL(sopbc_mfma, dim3(nblk, NB), dim3(256), 0, stream,
                           Er, Ei, ti, Bpack, out);
    } else {
        const int nblk = (TOUT + 255) / 256;
        hipLaunchKernelGGL(sopbc_scalar, dim3(nblk, NB), dim3(256), 0, stream,
                           Er, Ei, ti, pCr, pCi, C1r, C1i, C2r, C2i, out);
    }
}